// Round 5
// baseline (1442.537 us; speedup 1.0000x reference)
//
#include <hip/hip_runtime.h>
#include <math.h>

typedef unsigned short u16;
typedef __attribute__((ext_vector_type(8))) short short8;
typedef __attribute__((ext_vector_type(4))) short short4v;
typedef __attribute__((ext_vector_type(4))) float floatx4;

__device__ __forceinline__ float bf2f(u16 u) {
  union { unsigned int i; float f; } v; v.i = ((unsigned int)u) << 16; return v.f;
}
__device__ __forceinline__ u16 f2bf(float f) {
  union { unsigned int i; float f; } v; v.f = f;
  unsigned int i = v.i;
  unsigned int lsb = (i >> 16) & 1u;
  i += 0x7fffu + lsb;          // round-to-nearest-even
  return (u16)(i >> 16);
}

// ---------------------------------------------------------------------------
// Fused front GEMM: reads edge[E x 200] fp32 ONCE (coalesced float4),
// produces es = bf16(edge @ W_er^T + b_er) and Em = bf16(edge @ Wc^T + cm).
// ---------------------------------------------------------------------------
__global__ __launch_bounds__(256, 2)
void fused_front_k(const float* __restrict__ edge, const u16* __restrict__ Wcomb,
                   const float* __restrict__ b_er, const float* __restrict__ cmb,
                   u16* __restrict__ es, u16* __restrict__ Em)
{
  __shared__ __align__(16) u16 As[64 * 232];
  const int tid  = threadIdx.x;
  const int lane = tid & 63;
  const int wv   = tid >> 6;
  const int q    = lane >> 4;
  const int cl   = lane & 15;
  const long r0  = (long)blockIdx.x * 64;

  for (int z = tid; z < 64 * 24; z += 256) {
    const int zr = z / 24;
    As[zr * 232 + 200 + (z - zr * 24)] = 0;
  }
  const float4* src = (const float4*)(edge + r0 * 200);
  for (int it = tid; it < 3200; it += 256) {
    const float4 v = src[it];
    const int row = it / 50;
    const int c4  = it - row * 50;
    u16 t[4] = { f2bf(v.x), f2bf(v.y), f2bf(v.z), f2bf(v.w) };
    *(short4v*)&As[row * 232 + c4 * 4] = *(short4v*)t;
  }
  __syncthreads();

  floatx4 acc[4][8];
#pragma unroll
  for (int mi = 0; mi < 4; ++mi)
#pragma unroll
    for (int ni = 0; ni < 8; ++ni)
      acc[mi][ni] = (floatx4){0.f, 0.f, 0.f, 0.f};

  short8 b0[8], b1[8];
#pragma unroll
  for (int ni = 0; ni < 8; ++ni)
    b0[ni] = *(const short8*)(Wcomb + (long)(wv * 128 + ni * 16 + cl) * 224 + q * 8);
#pragma unroll
  for (int ks = 0; ks < 7; ++ks) {
    short8* bc = (ks & 1) ? b1 : b0;
    short8* bn = (ks & 1) ? b0 : b1;
    if (ks < 6) {
      const int kb = (ks + 1) * 32;
#pragma unroll
      for (int ni = 0; ni < 8; ++ni)
        bn[ni] = *(const short8*)(Wcomb + (long)(wv * 128 + ni * 16 + cl) * 224 + kb + q * 8);
    }
    short8 a[4];
#pragma unroll
    for (int mi = 0; mi < 4; ++mi)
      a[mi] = *(const short8*)&As[(mi * 16 + cl) * 232 + ks * 32 + q * 8];
#pragma unroll
    for (int mi = 0; mi < 4; ++mi)
#pragma unroll
      for (int ni = 0; ni < 8; ++ni)
        acc[mi][ni] = __builtin_amdgcn_mfma_f32_16x16x32_bf16(a[mi], bc[ni], acc[mi][ni], 0, 0, 0);
  }

  const bool is_ef   = (wv < 2);
  const float* bias  = is_ef ? b_er : cmb;
  u16* dst           = is_ef ? es : Em;
  const int colbase  = (wv & 1) * 128;
#pragma unroll
  for (int mi = 0; mi < 4; ++mi)
#pragma unroll
    for (int ni = 0; ni < 8; ++ni) {
      const int col = colbase + ni * 16 + cl;
      const float bb = bias[col];
#pragma unroll
      for (int r = 0; r < 4; ++r) {
        const int row = mi * 16 + q * 4 + r;
        dst[(r0 + row) * 256 + col] = f2bf(acc[mi][ni][r] + bb);
      }
    }
}

// ---------------------------------------------------------------------------
// Fused link MLP, 8-wave version (occupancy: 2 blocks/CU x 8 waves = 16 w/CU).
// Per block of 64 edge rows:
//   phase1: x1[64x512] = relu(es @ Wl1^T + bl1) -> LDS bf16 (stride 520,
//           XOR-swizzled 8-col chunks)
//   phase2: adj[64] = bl3 + sum_col relu(x1 @ Wl2^T + bl2)[r,col] * wl3[col]
// Each wave owns a 64-col slice (acc 64 regs -> AGPRs; ~4 waves/SIMD).
// ---------------------------------------------------------------------------
#define X1STRIDE 520
__global__ __launch_bounds__(512, 4)
void link_k(const u16* __restrict__ es, const u16* __restrict__ Wl1b,
            const float* __restrict__ bl1, const u16* __restrict__ Wl2b,
            const float* __restrict__ bl2, const float* __restrict__ wl3,
            const float* __restrict__ bl3, float* __restrict__ adj)
{
  __shared__ __align__(16) u16 x1b[64 * X1STRIDE];   // 66.6 KB
  const int tid  = threadIdx.x;
  const int lane = tid & 63;
  const int wv   = tid >> 6;        // wave 0..7 -> 64-col slice
  const int q    = lane >> 4;
  const int cl   = lane & 15;
  const int nw0  = wv * 64;
  const long r0  = (long)blockIdx.x * 64;

  floatx4 acc[4][4];
#pragma unroll
  for (int mi = 0; mi < 4; ++mi)
#pragma unroll
    for (int ni = 0; ni < 4; ++ni)
      acc[mi][ni] = (floatx4){0.f, 0.f, 0.f, 0.f};

  // ---------------- phase 1: x1 = relu(es @ Wl1^T + bl1) ----------------
  {
    short8 b0[4], b1[4];
#pragma unroll
    for (int ni = 0; ni < 4; ++ni)
      b0[ni] = *(const short8*)(Wl1b + (nw0 + ni * 16 + cl) * 256 + q * 8);
#pragma unroll
    for (int ks = 0; ks < 8; ++ks) {
      short8* bc = (ks & 1) ? b1 : b0;
      short8* bn = (ks & 1) ? b0 : b1;
      if (ks < 7) {
        const int kb = (ks + 1) * 32;
#pragma unroll
        for (int ni = 0; ni < 4; ++ni)
          bn[ni] = *(const short8*)(Wl1b + (nw0 + ni * 16 + cl) * 256 + kb + q * 8);
      }
      short8 a[4];
#pragma unroll
      for (int mi = 0; mi < 4; ++mi)
        a[mi] = *(const short8*)(es + (r0 + mi * 16 + cl) * 256 + ks * 32 + q * 8);
#pragma unroll
      for (int mi = 0; mi < 4; ++mi)
#pragma unroll
        for (int ni = 0; ni < 4; ++ni)
          acc[mi][ni] = __builtin_amdgcn_mfma_f32_16x16x32_bf16(a[mi], bc[ni], acc[mi][ni], 0, 0, 0);
    }
  }
  // epilogue 1: write x1 (bf16) into swizzled LDS
#pragma unroll
  for (int mi = 0; mi < 4; ++mi)
#pragma unroll
    for (int ni = 0; ni < 4; ++ni) {
      const int col = nw0 + ni * 16 + cl;
      const float bb = bl1[col];
      const int chunk = col >> 3;
#pragma unroll
      for (int r = 0; r < 4; ++r) {
        const int row = mi * 16 + q * 4 + r;
        const float v = fmaxf(acc[mi][ni][r] + bb, 0.f);
        x1b[row * X1STRIDE + (((chunk ^ (row & 7)) << 3) | (col & 7))] = f2bf(v);
      }
    }
#pragma unroll
  for (int mi = 0; mi < 4; ++mi)
#pragma unroll
    for (int ni = 0; ni < 4; ++ni)
      acc[mi][ni] = (floatx4){0.f, 0.f, 0.f, 0.f};
  __syncthreads();

  // ---------------- phase 2: acc = x1 @ Wl2^T ----------------
  {
    short8 b0[4], b1[4];
#pragma unroll
    for (int ni = 0; ni < 4; ++ni)
      b0[ni] = *(const short8*)(Wl2b + (nw0 + ni * 16 + cl) * 512 + q * 8);
#pragma unroll
    for (int ks = 0; ks < 16; ++ks) {
      short8* bc = (ks & 1) ? b1 : b0;
      short8* bn = (ks & 1) ? b0 : b1;
      if (ks < 15) {
        const int kb = (ks + 1) * 32;
#pragma unroll
        for (int ni = 0; ni < 4; ++ni)
          bn[ni] = *(const short8*)(Wl2b + (nw0 + ni * 16 + cl) * 512 + kb + q * 8);
      }
      short8 a[4];
#pragma unroll
      for (int mi = 0; mi < 4; ++mi) {
        const int row = mi * 16 + cl;
        const int chunk = ks * 4 + q;
        a[mi] = *(const short8*)&x1b[row * X1STRIDE + ((chunk ^ (row & 7)) << 3)];
      }
#pragma unroll
      for (int mi = 0; mi < 4; ++mi)
#pragma unroll
        for (int ni = 0; ni < 4; ++ni)
          acc[mi][ni] = __builtin_amdgcn_mfma_f32_16x16x32_bf16(a[mi], bc[ni], acc[mi][ni], 0, 0, 0);
    }
  }

  // epilogue 2: relu(+bl2), dot wl3, reduce to adj
  float pv[4][4];
#pragma unroll
  for (int mi = 0; mi < 4; ++mi)
#pragma unroll
    for (int r = 0; r < 4; ++r) pv[mi][r] = 0.f;
#pragma unroll
  for (int mi = 0; mi < 4; ++mi)
#pragma unroll
    for (int ni = 0; ni < 4; ++ni) {
      const int col = nw0 + ni * 16 + cl;
      const float bb = bl2[col];
      const float w3 = wl3[col];
#pragma unroll
      for (int r = 0; r < 4; ++r) {
        const float v = fmaxf(acc[mi][ni][r] + bb, 0.f);
        pv[mi][r] += v * w3;
      }
    }
  __syncthreads();                    // all x1b reads done; reuse as reduce buf
  float* pf = (float*)x1b;            // [8 waves][64 rows]
#pragma unroll
  for (int mi = 0; mi < 4; ++mi)
#pragma unroll
    for (int r = 0; r < 4; ++r) {
      float p = pv[mi][r];
#pragma unroll
      for (int off = 1; off < 16; off <<= 1)
        p += __shfl_xor(p, off, 64);
      if (cl == 0) pf[wv * 64 + mi * 16 + q * 4 + r] = p;
    }
  __syncthreads();
  if (tid < 64) {
    float s = bl3[0];
#pragma unroll
    for (int w = 0; w < 8; ++w) s += pf[w * 64 + tid];
    adj[r0 + tid] = s;
  }
}

// ---------------------------------------------------------------------------
// Split-precision MFMA GEMM (~fp32 accuracy) for the h path.
// ---------------------------------------------------------------------------
template<bool OUT_BF16>
__global__ __launch_bounds__(256, 2)
void gemm_sp_k(const float* __restrict__ A, const u16* __restrict__ Bh,
               const u16* __restrict__ Bl, const float* __restrict__ bias,
               void* __restrict__ Cp,
               int N, int K_loop, int K_src, int lda, int ldc)
{
  __shared__ __align__(16) u16 Ash[128 * 40];
  __shared__ __align__(16) u16 Asl[128 * 40];
  __shared__ __align__(16) u16 Bsh[128 * 40];
  __shared__ __align__(16) u16 Bsl[128 * 40];
  const int tid  = threadIdx.x;
  const int m0   = blockIdx.x * 128;
  const int n0   = blockIdx.y * 128;
  const int lane = tid & 63;
  const int wv   = tid >> 6;
  const int wm   = wv & 1;
  const int wn   = wv >> 1;
  const int q    = lane >> 4;
  const int cl   = lane & 15;

  floatx4 acc[4][4];
#pragma unroll
  for (int i = 0; i < 4; ++i)
#pragma unroll
    for (int j = 0; j < 4; ++j)
      acc[i][j] = (floatx4){0.f, 0.f, 0.f, 0.f};

  const int srow = tid >> 1;
  const int scol = (tid & 1) * 16;

  for (int kb = 0; kb < K_loop; kb += 32) {
    {
      const long r = (long)(m0 + srow);
      u16* dh = &Ash[srow * 40 + scol];
      u16* dl = &Asl[srow * 40 + scol];
#pragma unroll
      for (int j = 0; j < 16; ++j) {
        int kg = kb + scol + j;
        float v = (kg < K_src) ? A[r * lda + kg] : 0.f;
        u16 hi = f2bf(v);
        dh[j] = hi;
        dl[j] = f2bf(v - bf2f(hi));
      }
    }
    {
      const int n = n0 + srow;
      u16* dh = &Bsh[srow * 40 + scol];
      u16* dl = &Bsl[srow * 40 + scol];
      if (n < N) {
        const short8* sh = (const short8*)(Bh + (long)n * K_loop + kb + scol);
        const short8* sl = (const short8*)(Bl + (long)n * K_loop + kb + scol);
        ((short8*)dh)[0] = sh[0]; ((short8*)dh)[1] = sh[1];
        ((short8*)dl)[0] = sl[0]; ((short8*)dl)[1] = sl[1];
      } else {
#pragma unroll
        for (int j = 0; j < 16; ++j) { dh[j] = 0; dl[j] = 0; }
      }
    }
    __syncthreads();

    short8 ah[4], al[4], bh[4], bl[4];
#pragma unroll
    for (int mi = 0; mi < 4; ++mi) {
      ah[mi] = *(const short8*)&Ash[(wm * 64 + mi * 16 + cl) * 40 + q * 8];
      al[mi] = *(const short8*)&Asl[(wm * 64 + mi * 16 + cl) * 40 + q * 8];
    }
#pragma unroll
    for (int ni = 0; ni < 4; ++ni) {
      bh[ni] = *(const short8*)&Bsh[(wn * 64 + ni * 16 + cl) * 40 + q * 8];
      bl[ni] = *(const short8*)&Bsl[(wn * 64 + ni * 16 + cl) * 40 + q * 8];
    }
#pragma unroll
    for (int mi = 0; mi < 4; ++mi)
#pragma unroll
      for (int ni = 0; ni < 4; ++ni) {
        acc[mi][ni] = __builtin_amdgcn_mfma_f32_16x16x32_bf16(ah[mi], bh[ni], acc[mi][ni], 0, 0, 0);
        acc[mi][ni] = __builtin_amdgcn_mfma_f32_16x16x32_bf16(al[mi], bh[ni], acc[mi][ni], 0, 0, 0);
        acc[mi][ni] = __builtin_amdgcn_mfma_f32_16x16x32_bf16(ah[mi], bl[ni], acc[mi][ni], 0, 0, 0);
      }
    __syncthreads();
  }

#pragma unroll
  for (int mi = 0; mi < 4; ++mi) {
    const int row = m0 + wm * 64 + mi * 16 + q * 4;
#pragma unroll
    for (int ni = 0; ni < 4; ++ni) {
      const int col = n0 + wn * 64 + ni * 16 + cl;
      if (col < N) {
        const float b = bias ? bias[col] : 0.f;
#pragma unroll
        for (int r = 0; r < 4; ++r) {
          float v = acc[mi][ni][r] + b;
          const long off = (long)(row + r) * ldc + col;
          if (OUT_BF16) ((u16*)Cp)[off] = f2bf(v);
          else          ((float*)Cp)[off] = v;
        }
      }
    }
  }
}

__global__ void cast_pad_k(u16* __restrict__ dst, const float* __restrict__ src,
                           int rows, int src_cols, int dst_cols, int src_stride,
                           int col_off)
{
  int idx = blockIdx.x * blockDim.x + threadIdx.x;
  int total = rows * dst_cols;
  if (idx >= total) return;
  int r = idx / dst_cols, c = idx - r * dst_cols;
  float v = (c < src_cols) ? src[r * src_stride + col_off + c] : 0.f;
  dst[idx] = f2bf(v);
}

__global__ void cast_split_k(u16* __restrict__ dh, u16* __restrict__ dl,
                             const float* __restrict__ src,
                             int rows, int src_cols, int dst_cols, int src_stride,
                             int col_off)
{
  int idx = blockIdx.x * blockDim.x + threadIdx.x;
  int total = rows * dst_cols;
  if (idx >= total) return;
  int r = idx / dst_cols, c = idx - r * dst_cols;
  float v = (c < src_cols) ? src[r * src_stride + col_off + c] : 0.f;
  u16 hi = f2bf(v);
  dh[idx] = hi;
  dl[idx] = f2bf(v - bf2f(hi));
}

// Wcf = W_me @ W_er (fp32, [256 x 224] zero-padded); c_m = W_me @ b_er + b_m
__global__ void wc_k(float* __restrict__ Wcf, float* __restrict__ cm,
                     const float* __restrict__ W_m, const float* __restrict__ W_er,
                     const float* __restrict__ b_er, const float* __restrict__ b_m)
{
  int o = blockIdx.x;
  int t = threadIdx.x;
  __shared__ float wme[256];
  wme[t] = W_m[o * 512 + 256 + t];
  __syncthreads();
  if (t < 224) {
    float s = 0.f;
    if (t < 200) {
      for (int c = 0; c < 256; ++c) s += wme[c] * W_er[c * 200 + t];
    }
    Wcf[o * 224 + t] = s;
  }
  if (t == 0) {
    float s = 0.f;
    for (int c = 0; c < 256; ++c) s += wme[c] * b_er[c];
    cm[o] = s + b_m[o];
  }
}

// Per-edge message + transpose-scatter + per-target aggregation.
__global__ __launch_bounds__(256)
void message_k(const u16* __restrict__ Em, const float* __restrict__ Hm,
               const float* __restrict__ adj, u16* __restrict__ es,
               float* __restrict__ msum)
{
  const int b = blockIdx.y, i = blockIdx.x;
  const int tid = threadIdx.x;
  const int c = tid & 31;
  const int g = tid >> 5;
  __shared__ float red[8][256];
  float accv[8] = {0.f, 0.f, 0.f, 0.f, 0.f, 0.f, 0.f, 0.f};
  const long base_bi = ((long)(b * 128 + i)) * 128;
  for (int w0 = 0; w0 < 128; w0 += 8) {
    const int w = w0 + g;
    const float a = adj[base_bi + w];
    const float s = 1.f / (1.f + __expf(-a));
    const short8 ev = *(const short8*)(Em + (base_bi + w) * 256 + c * 8);
    const float* hp = Hm + ((long)(b * 128 + w)) * 256 + c * 8;
    u16 mb[8];
#pragma unroll
    for (int j = 0; j < 8; ++j) {
      float x = bf2f(((const u16*)&ev)[j]) + hp[j];
      x = fmaxf(x, 0.f) * s;
      accv[j] += x;
      mb[j] = f2bf(x);
    }
    *(short8*)(es + (((long)(b * 128 + w)) * 128 + i) * 256 + c * 8) = *(short8*)mb;
  }
#pragma unroll
  for (int j = 0; j < 8; ++j) red[g][c * 8 + j] = accv[j];
  __syncthreads();
  float s = 0.f;
#pragma unroll
  for (int gg = 0; gg < 8; ++gg) s += red[gg][tid];
  msum[((long)(b * 128 + i)) * 256 + tid] = s;
}

__global__ void gru_k(const float* __restrict__ gi, const float* __restrict__ gh,
                      float* __restrict__ h)
{
  const int n = blockIdx.x;
  const int d = threadIdx.x;
  const int base = n * 768;
  const float r  = 1.f / (1.f + __expf(-(gi[base + d] + gh[base + d])));
  const float z  = 1.f / (1.f + __expf(-(gi[base + 256 + d] + gh[base + 256 + d])));
  const float nn = tanhf(gi[base + 512 + d] + r * gh[base + 512 + d]);
  const int hi = n * 256 + d;
  h[hi] = (1.f - z) * nn + z * h[hi];
}

extern "C" void kernel_launch(void* const* d_in, const int* in_sizes, int n_in,
                              void* d_out, int out_size, void* d_ws, size_t ws_size,
                              hipStream_t stream)
{
  const float* edge = (const float*)d_in[0];
  const float* node = (const float*)d_in[1];
  const float* W_er = (const float*)d_in[2];
  const float* b_er = (const float*)d_in[3];
  const float* W_nr = (const float*)d_in[4];
  const float* b_nr = (const float*)d_in[5];
  const float* Wl1  = (const float*)d_in[6];
  const float* bl1  = (const float*)d_in[7];
  const float* Wl2  = (const float*)d_in[8];
  const float* bl2  = (const float*)d_in[9];
  const float* Wl3  = (const float*)d_in[10];
  const float* bl3  = (const float*)d_in[11];
  const float* W_m  = (const float*)d_in[12];
  const float* b_m  = (const float*)d_in[13];
  const float* W_ih = (const float*)d_in[14];
  const float* b_ih = (const float*)d_in[15];
  const float* W_hh = (const float*)d_in[16];
  const float* b_hh = (const float*)d_in[17];
  const float* W_r  = (const float*)d_in[18];
  const float* b_r  = (const float*)d_in[19];
  (void)in_sizes; (void)n_in; (void)out_size; (void)ws_size;

  float* out_adj = (float*)d_out;            // [8,128,128]
  float* out_lab = (float*)d_out + 131072;   // [8,128,117]

  char* ws = (char*)d_ws;
  size_t off = 0;
  auto alloc = [&](size_t bytes) -> void* {
    void* p = ws + off; off += (bytes + 255) & ~(size_t)255; return p;
  };
  const long E = 131072;
  u16*   es   = (u16*)  alloc(E * 256 * 2);
  u16*   Em   = (u16*)  alloc(E * 256 * 2);
  float* Hm   = (float*)alloc(1024 * 256 * 4);
  float* hbuf = (float*)alloc(1024 * 256 * 4);
  float* msum = (float*)alloc(1024 * 256 * 4);
  float* gi   = (float*)alloc(1024 * 768 * 4);
  float* gh   = (float*)alloc(1024 * 768 * 4);
  u16*   Wcomb = (u16*) alloc(512 * 224 * 2); // [W_er ; W_me@W_er] bf16
  u16*   Wl1b = (u16*)  alloc(512 * 256 * 2);
  u16*   Wl2b = (u16*)  alloc(512 * 512 * 2);
  float* Wcf  = (float*)alloc(256 * 224 * 4);
  float* cmb  = (float*)alloc(256 * 4);
  u16* Wnr_h = (u16*)alloc(256 * 128 * 2); u16* Wnr_l = (u16*)alloc(256 * 128 * 2);
  u16* Wmh_h = (u16*)alloc(256 * 256 * 2); u16* Wmh_l = (u16*)alloc(256 * 256 * 2);
  u16* Wih_h = (u16*)alloc(768 * 256 * 2); u16* Wih_l = (u16*)alloc(768 * 256 * 2);
  u16* Whh_h = (u16*)alloc(768 * 256 * 2); u16* Whh_l = (u16*)alloc(768 * 256 * 2);
  u16* Wr_h  = (u16*)alloc(117 * 256 * 2); u16* Wr_l  = (u16*)alloc(117 * 256 * 2);

  auto cast = [&](u16* dst, const float* src, int rows, int sc, int dc,
                  int stride, int coff) {
    int total = rows * dc;
    cast_pad_k<<<(total + 255) / 256, 256, 0, stream>>>(dst, src, rows, sc, dc,
                                                        stride, coff);
  };
  auto split = [&](u16* dh, u16* dl, const float* src, int rows, int sc, int dc,
                   int stride, int coff) {
    int total = rows * dc;
    cast_split_k<<<(total + 255) / 256, 256, 0, stream>>>(dh, dl, src, rows, sc,
                                                          dc, stride, coff);
  };
  cast(Wcomb, W_er, 256, 200, 224, 200, 0);               // rows 0..255
  wc_k<<<256, 256, 0, stream>>>(Wcf, cmb, W_m, W_er, b_er, b_m);
  cast(Wcomb + 256 * 224, Wcf, 256, 224, 224, 224, 0);    // rows 256..511
  cast(Wl1b, Wl1, 512, 256, 256, 256, 0);
  cast(Wl2b, Wl2, 512, 512, 512, 512, 0);
  split(Wnr_h, Wnr_l, W_nr, 256, 100, 128, 100, 0);
  split(Wmh_h, Wmh_l, W_m, 256, 256, 256, 512, 0);
  split(Wih_h, Wih_l, W_ih, 768, 256, 256, 256, 0);
  split(Whh_h, Whh_l, W_hh, 768, 256, 256, 256, 0);
  split(Wr_h,  Wr_l,  W_r, 117, 256, 256, 256, 0);

  const dim3 blk(256);
  // es (layer-0 e_state) + Em in one pass, edge read once
  fused_front_k<<<2048, blk, 0, stream>>>(edge, Wcomb, b_er, cmb, es, Em);
  // h0 = node @ W_nr^T + b_nr
  gemm_sp_k<false><<<dim3(8, 2), blk, 0, stream>>>(
      node, Wnr_h, Wnr_l, b_nr, hbuf, 256, 128, 100, 100, 256);

  for (int p = 0; p < 3; ++p) {
    // Hm = h @ W_mh^T
    gemm_sp_k<false><<<dim3(8, 2), blk, 0, stream>>>(
        hbuf, Wmh_h, Wmh_l, nullptr, Hm, 256, 256, 256, 256, 256);
    // fused link MLP -> adj (writes out_adj directly, incl. bl3)
    link_k<<<2048, dim3(512), 0, stream>>>(es, Wl1b, bl1, Wl2b, bl2, Wl3, bl3, out_adj);
    // messages, transpose-scatter into e_state, aggregate msum
    message_k<<<dim3(128, 8), blk, 0, stream>>>(Em, Hm, out_adj, es, msum);
    // GRU gates
    gemm_sp_k<false><<<dim3(8, 6), blk, 0, stream>>>(
        msum, Wih_h, Wih_l, b_ih, gi, 768, 256, 256, 256, 768);
    gemm_sp_k<false><<<dim3(8, 6), blk, 0, stream>>>(
        hbuf, Whh_h, Whh_l, b_hh, gh, 768, 256, 256, 256, 768);
    gru_k<<<1024, 256, 0, stream>>>(gi, gh, hbuf);
  }
  // labels = h @ W_r^T + b_r
  gemm_sp_k<false><<<dim3(8, 1), blk, 0, stream>>>(
      hbuf, Wr_h, Wr_l, b_r, out_lab, 117, 256, 256, 256, 117);
}

// Round 6
// 1200.266 us; speedup vs baseline: 1.2018x; 1.2018x over previous
//
#include <hip/hip_runtime.h>
#include <math.h>

typedef unsigned short u16;
typedef __attribute__((ext_vector_type(8))) short short8;
typedef __attribute__((ext_vector_type(4))) short short4v;
typedef __attribute__((ext_vector_type(4))) float floatx4;

__device__ __forceinline__ float bf2f(u16 u) {
  union { unsigned int i; float f; } v; v.i = ((unsigned int)u) << 16; return v.f;
}
__device__ __forceinline__ u16 f2bf(float f) {
  union { unsigned int i; float f; } v; v.f = f;
  unsigned int i = v.i;
  unsigned int lsb = (i >> 16) & 1u;
  i += 0x7fffu + lsb;          // round-to-nearest-even
  return (u16)(i >> 16);
}

// ---------------------------------------------------------------------------
// Fused front GEMM: reads edge[E x 200] fp32 ONCE (coalesced float4),
// produces es = bf16(edge @ W_er^T + b_er) and Em = bf16(edge @ Wc^T + cm).
// ---------------------------------------------------------------------------
__global__ __launch_bounds__(256, 2)
void fused_front_k(const float* __restrict__ edge, const u16* __restrict__ Wcomb,
                   const float* __restrict__ b_er, const float* __restrict__ cmb,
                   u16* __restrict__ es, u16* __restrict__ Em)
{
  __shared__ __align__(16) u16 As[64 * 232];
  const int tid  = threadIdx.x;
  const int lane = tid & 63;
  const int wv   = tid >> 6;
  const int q    = lane >> 4;
  const int cl   = lane & 15;
  const long r0  = (long)blockIdx.x * 64;

  for (int z = tid; z < 64 * 24; z += 256) {
    const int zr = z / 24;
    As[zr * 232 + 200 + (z - zr * 24)] = 0;
  }
  const float4* src = (const float4*)(edge + r0 * 200);
  for (int it = tid; it < 3200; it += 256) {
    const float4 v = src[it];
    const int row = it / 50;
    const int c4  = it - row * 50;
    u16 t[4] = { f2bf(v.x), f2bf(v.y), f2bf(v.z), f2bf(v.w) };
    *(short4v*)&As[row * 232 + c4 * 4] = *(short4v*)t;
  }
  __syncthreads();

  floatx4 acc[4][8];
#pragma unroll
  for (int mi = 0; mi < 4; ++mi)
#pragma unroll
    for (int ni = 0; ni < 8; ++ni)
      acc[mi][ni] = (floatx4){0.f, 0.f, 0.f, 0.f};

  short8 b0[8], b1[8];
#pragma unroll
  for (int ni = 0; ni < 8; ++ni)
    b0[ni] = *(const short8*)(Wcomb + (long)(wv * 128 + ni * 16 + cl) * 224 + q * 8);
#pragma unroll
  for (int ks = 0; ks < 7; ++ks) {
    short8* bc = (ks & 1) ? b1 : b0;
    short8* bn = (ks & 1) ? b0 : b1;
    if (ks < 6) {
      const int kb = (ks + 1) * 32;
#pragma unroll
      for (int ni = 0; ni < 8; ++ni)
        bn[ni] = *(const short8*)(Wcomb + (long)(wv * 128 + ni * 16 + cl) * 224 + kb + q * 8);
    }
    short8 a[4];
#pragma unroll
    for (int mi = 0; mi < 4; ++mi)
      a[mi] = *(const short8*)&As[(mi * 16 + cl) * 232 + ks * 32 + q * 8];
#pragma unroll
    for (int mi = 0; mi < 4; ++mi)
#pragma unroll
      for (int ni = 0; ni < 8; ++ni)
        acc[mi][ni] = __builtin_amdgcn_mfma_f32_16x16x32_bf16(a[mi], bc[ni], acc[mi][ni], 0, 0, 0);
  }

  const bool is_ef   = (wv < 2);
  const float* bias  = is_ef ? b_er : cmb;
  u16* dst           = is_ef ? es : Em;
  const int colbase  = (wv & 1) * 128;
#pragma unroll
  for (int mi = 0; mi < 4; ++mi)
#pragma unroll
    for (int ni = 0; ni < 8; ++ni) {
      const int col = colbase + ni * 16 + cl;
      const float bb = bias[col];
#pragma unroll
      for (int r = 0; r < 4; ++r) {
        const int row = mi * 16 + q * 4 + r;
        dst[(r0 + row) * 256 + col] = f2bf(acc[mi][ni][r] + bb);
      }
    }
}

// ---------------------------------------------------------------------------
// Fused link MLP, 128-rows-per-block version.
// Rationale (R5 post-mortem): the binding constraint is WEIGHT RE-STREAMING —
// every block pulls 768 KB (Wl1+Wl2) through L2/L3. 128 rows/block halves
// block count (1024): 786 MB/layer instead of 1.57 GB, and doubles MFMA work
// per weight load (32 MFMA per 4 loads). x1[128x512] bf16 lives in LDS
// (128 KB, 1 block/CU). Stride-512 XOR swizzle (measured 2.1M conflicts in
// R4; the 520-stride variant measured 16.8M — do not repeat).
// ---------------------------------------------------------------------------
__global__ __launch_bounds__(512, 2)
void link_k(const u16* __restrict__ es, const u16* __restrict__ Wl1b,
            const float* __restrict__ bl1, const u16* __restrict__ Wl2b,
            const float* __restrict__ bl2, const float* __restrict__ wl3,
            const float* __restrict__ bl3, float* __restrict__ adj)
{
  __shared__ __align__(16) u16 x1b[128 * 512];   // 128 KB
  const int tid  = threadIdx.x;
  const int lane = tid & 63;
  const int wv   = tid >> 6;        // wave 0..7 -> 64-col slice
  const int q    = lane >> 4;
  const int cl   = lane & 15;
  const int nw0  = wv * 64;
  const long r0  = (long)blockIdx.x * 128;

  floatx4 acc[8][4];
#pragma unroll
  for (int mi = 0; mi < 8; ++mi)
#pragma unroll
    for (int ni = 0; ni < 4; ++ni)
      acc[mi][ni] = (floatx4){0.f, 0.f, 0.f, 0.f};

  // ---------------- phase 1: x1 = relu(es @ Wl1^T + bl1) ----------------
  {
    short8 b0[4], b1[4];
#pragma unroll
    for (int ni = 0; ni < 4; ++ni)
      b0[ni] = *(const short8*)(Wl1b + (nw0 + ni * 16 + cl) * 256 + q * 8);
#pragma unroll
    for (int ks = 0; ks < 8; ++ks) {
      short8* bc = (ks & 1) ? b1 : b0;
      short8* bn = (ks & 1) ? b0 : b1;
      if (ks < 7) {
        const int kb = (ks + 1) * 32;
#pragma unroll
        for (int ni = 0; ni < 4; ++ni)
          bn[ni] = *(const short8*)(Wl1b + (nw0 + ni * 16 + cl) * 256 + kb + q * 8);
      }
      short8 a[8];
#pragma unroll
      for (int mi = 0; mi < 8; ++mi)
        a[mi] = *(const short8*)(es + (r0 + mi * 16 + cl) * 256 + ks * 32 + q * 8);
#pragma unroll
      for (int mi = 0; mi < 8; ++mi)
#pragma unroll
        for (int ni = 0; ni < 4; ++ni)
          acc[mi][ni] = __builtin_amdgcn_mfma_f32_16x16x32_bf16(a[mi], bc[ni], acc[mi][ni], 0, 0, 0);
    }
  }
  // epilogue 1: write x1 (bf16) into XOR-swizzled LDS (stride 512)
#pragma unroll
  for (int mi = 0; mi < 8; ++mi)
#pragma unroll
    for (int ni = 0; ni < 4; ++ni) {
      const int col = nw0 + ni * 16 + cl;
      const float bb = bl1[col];
      const int chunk = col >> 3;
#pragma unroll
      for (int r = 0; r < 4; ++r) {
        const int row = mi * 16 + q * 4 + r;
        const float v = fmaxf(acc[mi][ni][r] + bb, 0.f);
        x1b[row * 512 + (((chunk ^ (row & 7)) << 3) | (col & 7))] = f2bf(v);
      }
    }
#pragma unroll
  for (int mi = 0; mi < 8; ++mi)
#pragma unroll
    for (int ni = 0; ni < 4; ++ni)
      acc[mi][ni] = (floatx4){0.f, 0.f, 0.f, 0.f};
  __syncthreads();

  // ---------------- phase 2: acc = x1 @ Wl2^T ----------------
  {
    short8 b0[4], b1[4];
#pragma unroll
    for (int ni = 0; ni < 4; ++ni)
      b0[ni] = *(const short8*)(Wl2b + (nw0 + ni * 16 + cl) * 512 + q * 8);
#pragma unroll
    for (int ks = 0; ks < 16; ++ks) {
      short8* bc = (ks & 1) ? b1 : b0;
      short8* bn = (ks & 1) ? b0 : b1;
      if (ks < 15) {
        const int kb = (ks + 1) * 32;
#pragma unroll
        for (int ni = 0; ni < 4; ++ni)
          bn[ni] = *(const short8*)(Wl2b + (nw0 + ni * 16 + cl) * 512 + kb + q * 8);
      }
      short8 a[8];
#pragma unroll
      for (int mi = 0; mi < 8; ++mi) {
        const int row = mi * 16 + cl;
        const int chunk = ks * 4 + q;
        a[mi] = *(const short8*)&x1b[row * 512 + ((chunk ^ (row & 7)) << 3)];
      }
#pragma unroll
      for (int mi = 0; mi < 8; ++mi)
#pragma unroll
        for (int ni = 0; ni < 4; ++ni)
          acc[mi][ni] = __builtin_amdgcn_mfma_f32_16x16x32_bf16(a[mi], bc[ni], acc[mi][ni], 0, 0, 0);
    }
  }

  // epilogue 2: relu(+bl2), dot wl3, reduce to adj
  float pv[8][4];
#pragma unroll
  for (int mi = 0; mi < 8; ++mi)
#pragma unroll
    for (int r = 0; r < 4; ++r) pv[mi][r] = 0.f;
#pragma unroll
  for (int mi = 0; mi < 8; ++mi)
#pragma unroll
    for (int ni = 0; ni < 4; ++ni) {
      const int col = nw0 + ni * 16 + cl;
      const float bb = bl2[col];
      const float w3 = wl3[col];
#pragma unroll
      for (int r = 0; r < 4; ++r) {
        const float v = fmaxf(acc[mi][ni][r] + bb, 0.f);
        pv[mi][r] += v * w3;
      }
    }
  __syncthreads();                    // all x1b reads done; reuse as reduce buf
  float* pf = (float*)x1b;            // [8 waves][128 rows]
#pragma unroll
  for (int mi = 0; mi < 8; ++mi)
#pragma unroll
    for (int r = 0; r < 4; ++r) {
      float p = pv[mi][r];
#pragma unroll
      for (int off = 1; off < 16; off <<= 1)
        p += __shfl_xor(p, off, 64);
      if (cl == 0) pf[wv * 128 + mi * 16 + q * 4 + r] = p;
    }
  __syncthreads();
  if (tid < 128) {
    float s = bl3[0];
#pragma unroll
    for (int w = 0; w < 8; ++w) s += pf[w * 128 + tid];
    adj[r0 + tid] = s;
  }
}

// ---------------------------------------------------------------------------
// Split-precision MFMA GEMM (~fp32 accuracy) for the h path.
// ---------------------------------------------------------------------------
template<bool OUT_BF16>
__global__ __launch_bounds__(256, 2)
void gemm_sp_k(const float* __restrict__ A, const u16* __restrict__ Bh,
               const u16* __restrict__ Bl, const float* __restrict__ bias,
               void* __restrict__ Cp,
               int N, int K_loop, int K_src, int lda, int ldc)
{
  __shared__ __align__(16) u16 Ash[128 * 40];
  __shared__ __align__(16) u16 Asl[128 * 40];
  __shared__ __align__(16) u16 Bsh[128 * 40];
  __shared__ __align__(16) u16 Bsl[128 * 40];
  const int tid  = threadIdx.x;
  const int m0   = blockIdx.x * 128;
  const int n0   = blockIdx.y * 128;
  const int lane = tid & 63;
  const int wv   = tid >> 6;
  const int wm   = wv & 1;
  const int wn   = wv >> 1;
  const int q    = lane >> 4;
  const int cl   = lane & 15;

  floatx4 acc[4][4];
#pragma unroll
  for (int i = 0; i < 4; ++i)
#pragma unroll
    for (int j = 0; j < 4; ++j)
      acc[i][j] = (floatx4){0.f, 0.f, 0.f, 0.f};

  const int srow = tid >> 1;
  const int scol = (tid & 1) * 16;

  for (int kb = 0; kb < K_loop; kb += 32) {
    {
      const long r = (long)(m0 + srow);
      u16* dh = &Ash[srow * 40 + scol];
      u16* dl = &Asl[srow * 40 + scol];
#pragma unroll
      for (int j = 0; j < 16; ++j) {
        int kg = kb + scol + j;
        float v = (kg < K_src) ? A[r * lda + kg] : 0.f;
        u16 hi = f2bf(v);
        dh[j] = hi;
        dl[j] = f2bf(v - bf2f(hi));
      }
    }
    {
      const int n = n0 + srow;
      u16* dh = &Bsh[srow * 40 + scol];
      u16* dl = &Bsl[srow * 40 + scol];
      if (n < N) {
        const short8* sh = (const short8*)(Bh + (long)n * K_loop + kb + scol);
        const short8* sl = (const short8*)(Bl + (long)n * K_loop + kb + scol);
        ((short8*)dh)[0] = sh[0]; ((short8*)dh)[1] = sh[1];
        ((short8*)dl)[0] = sl[0]; ((short8*)dl)[1] = sl[1];
      } else {
#pragma unroll
        for (int j = 0; j < 16; ++j) { dh[j] = 0; dl[j] = 0; }
      }
    }
    __syncthreads();

    short8 ah[4], al[4], bh[4], bl[4];
#pragma unroll
    for (int mi = 0; mi < 4; ++mi) {
      ah[mi] = *(const short8*)&Ash[(wm * 64 + mi * 16 + cl) * 40 + q * 8];
      al[mi] = *(const short8*)&Asl[(wm * 64 + mi * 16 + cl) * 40 + q * 8];
    }
#pragma unroll
    for (int ni = 0; ni < 4; ++ni) {
      bh[ni] = *(const short8*)&Bsh[(wn * 64 + ni * 16 + cl) * 40 + q * 8];
      bl[ni] = *(const short8*)&Bsl[(wn * 64 + ni * 16 + cl) * 40 + q * 8];
    }
#pragma unroll
    for (int mi = 0; mi < 4; ++mi)
#pragma unroll
      for (int ni = 0; ni < 4; ++ni) {
        acc[mi][ni] = __builtin_amdgcn_mfma_f32_16x16x32_bf16(ah[mi], bh[ni], acc[mi][ni], 0, 0, 0);
        acc[mi][ni] = __builtin_amdgcn_mfma_f32_16x16x32_bf16(al[mi], bh[ni], acc[mi][ni], 0, 0, 0);
        acc[mi][ni] = __builtin_amdgcn_mfma_f32_16x16x32_bf16(ah[mi], bl[ni], acc[mi][ni], 0, 0, 0);
      }
    __syncthreads();
  }

#pragma unroll
  for (int mi = 0; mi < 4; ++mi) {
    const int row = m0 + wm * 64 + mi * 16 + q * 4;
#pragma unroll
    for (int ni = 0; ni < 4; ++ni) {
      const int col = n0 + wn * 64 + ni * 16 + cl;
      if (col < N) {
        const float b = bias ? bias[col] : 0.f;
#pragma unroll
        for (int r = 0; r < 4; ++r) {
          float v = acc[mi][ni][r] + b;
          const long off = (long)(row + r) * ldc + col;
          if (OUT_BF16) ((u16*)Cp)[off] = f2bf(v);
          else          ((float*)Cp)[off] = v;
        }
      }
    }
  }
}

__global__ void cast_pad_k(u16* __restrict__ dst, const float* __restrict__ src,
                           int rows, int src_cols, int dst_cols, int src_stride,
                           int col_off)
{
  int idx = blockIdx.x * blockDim.x + threadIdx.x;
  int total = rows * dst_cols;
  if (idx >= total) return;
  int r = idx / dst_cols, c = idx - r * dst_cols;
  float v = (c < src_cols) ? src[r * src_stride + col_off + c] : 0.f;
  dst[idx] = f2bf(v);
}

__global__ void cast_split_k(u16* __restrict__ dh, u16* __restrict__ dl,
                             const float* __restrict__ src,
                             int rows, int src_cols, int dst_cols, int src_stride,
                             int col_off)
{
  int idx = blockIdx.x * blockDim.x + threadIdx.x;
  int total = rows * dst_cols;
  if (idx >= total) return;
  int r = idx / dst_cols, c = idx - r * dst_cols;
  float v = (c < src_cols) ? src[r * src_stride + col_off + c] : 0.f;
  u16 hi = f2bf(v);
  dh[idx] = hi;
  dl[idx] = f2bf(v - bf2f(hi));
}

// Wcf = W_me @ W_er (fp32, [256 x 224] zero-padded); c_m = W_me @ b_er + b_m
__global__ void wc_k(float* __restrict__ Wcf, float* __restrict__ cm,
                     const float* __restrict__ W_m, const float* __restrict__ W_er,
                     const float* __restrict__ b_er, const float* __restrict__ b_m)
{
  int o = blockIdx.x;
  int t = threadIdx.x;
  __shared__ float wme[256];
  wme[t] = W_m[o * 512 + 256 + t];
  __syncthreads();
  if (t < 224) {
    float s = 0.f;
    if (t < 200) {
      for (int c = 0; c < 256; ++c) s += wme[c] * W_er[c * 200 + t];
    }
    Wcf[o * 224 + t] = s;
  }
  if (t == 0) {
    float s = 0.f;
    for (int c = 0; c < 256; ++c) s += wme[c] * b_er[c];
    cm[o] = s + b_m[o];
  }
}

// Per-edge message + transpose-scatter + per-target aggregation.
__global__ __launch_bounds__(256)
void message_k(const u16* __restrict__ Em, const float* __restrict__ Hm,
               const float* __restrict__ adj, u16* __restrict__ es,
               float* __restrict__ msum)
{
  const int b = blockIdx.y, i = blockIdx.x;
  const int tid = threadIdx.x;
  const int c = tid & 31;
  const int g = tid >> 5;
  __shared__ float red[8][256];
  float accv[8] = {0.f, 0.f, 0.f, 0.f, 0.f, 0.f, 0.f, 0.f};
  const long base_bi = ((long)(b * 128 + i)) * 128;
  for (int w0 = 0; w0 < 128; w0 += 8) {
    const int w = w0 + g;
    const float a = adj[base_bi + w];
    const float s = 1.f / (1.f + __expf(-a));
    const short8 ev = *(const short8*)(Em + (base_bi + w) * 256 + c * 8);
    const float* hp = Hm + ((long)(b * 128 + w)) * 256 + c * 8;
    u16 mb[8];
#pragma unroll
    for (int j = 0; j < 8; ++j) {
      float x = bf2f(((const u16*)&ev)[j]) + hp[j];
      x = fmaxf(x, 0.f) * s;
      accv[j] += x;
      mb[j] = f2bf(x);
    }
    *(short8*)(es + (((long)(b * 128 + w)) * 128 + i) * 256 + c * 8) = *(short8*)mb;
  }
#pragma unroll
  for (int j = 0; j < 8; ++j) red[g][c * 8 + j] = accv[j];
  __syncthreads();
  float s = 0.f;
#pragma unroll
  for (int gg = 0; gg < 8; ++gg) s += red[gg][tid];
  msum[((long)(b * 128 + i)) * 256 + tid] = s;
}

__global__ void gru_k(const float* __restrict__ gi, const float* __restrict__ gh,
                      float* __restrict__ h)
{
  const int n = blockIdx.x;
  const int d = threadIdx.x;
  const int base = n * 768;
  const float r  = 1.f / (1.f + __expf(-(gi[base + d] + gh[base + d])));
  const float z  = 1.f / (1.f + __expf(-(gi[base + 256 + d] + gh[base + 256 + d])));
  const float nn = tanhf(gi[base + 512 + d] + r * gh[base + 512 + d]);
  const int hi = n * 256 + d;
  h[hi] = (1.f - z) * nn + z * h[hi];
}

extern "C" void kernel_launch(void* const* d_in, const int* in_sizes, int n_in,
                              void* d_out, int out_size, void* d_ws, size_t ws_size,
                              hipStream_t stream)
{
  const float* edge = (const float*)d_in[0];
  const float* node = (const float*)d_in[1];
  const float* W_er = (const float*)d_in[2];
  const float* b_er = (const float*)d_in[3];
  const float* W_nr = (const float*)d_in[4];
  const float* b_nr = (const float*)d_in[5];
  const float* Wl1  = (const float*)d_in[6];
  const float* bl1  = (const float*)d_in[7];
  const float* Wl2  = (const float*)d_in[8];
  const float* bl2  = (const float*)d_in[9];
  const float* Wl3  = (const float*)d_in[10];
  const float* bl3  = (const float*)d_in[11];
  const float* W_m  = (const float*)d_in[12];
  const float* b_m  = (const float*)d_in[13];
  const float* W_ih = (const float*)d_in[14];
  const float* b_ih = (const float*)d_in[15];
  const float* W_hh = (const float*)d_in[16];
  const float* b_hh = (const float*)d_in[17];
  const float* W_r  = (const float*)d_in[18];
  const float* b_r  = (const float*)d_in[19];
  (void)in_sizes; (void)n_in; (void)out_size; (void)ws_size;

  float* out_adj = (float*)d_out;            // [8,128,128]
  float* out_lab = (float*)d_out + 131072;   // [8,128,117]

  char* ws = (char*)d_ws;
  size_t off = 0;
  auto alloc = [&](size_t bytes) -> void* {
    void* p = ws + off; off += (bytes + 255) & ~(size_t)255; return p;
  };
  const long E = 131072;
  u16*   es   = (u16*)  alloc(E * 256 * 2);
  u16*   Em   = (u16*)  alloc(E * 256 * 2);
  float* Hm   = (float*)alloc(1024 * 256 * 4);
  float* hbuf = (float*)alloc(1024 * 256 * 4);
  float* msum = (float*)alloc(1024 * 256 * 4);
  float* gi   = (float*)alloc(1024 * 768 * 4);
  float* gh   = (float*)alloc(1024 * 768 * 4);
  u16*   Wcomb = (u16*) alloc(512 * 224 * 2); // [W_er ; W_me@W_er] bf16
  u16*   Wl1b = (u16*)  alloc(512 * 256 * 2);
  u16*   Wl2b = (u16*)  alloc(512 * 512 * 2);
  float* Wcf  = (float*)alloc(256 * 224 * 4);
  float* cmb  = (float*)alloc(256 * 4);
  u16* Wnr_h = (u16*)alloc(256 * 128 * 2); u16* Wnr_l = (u16*)alloc(256 * 128 * 2);
  u16* Wmh_h = (u16*)alloc(256 * 256 * 2); u16* Wmh_l = (u16*)alloc(256 * 256 * 2);
  u16* Wih_h = (u16*)alloc(768 * 256 * 2); u16* Wih_l = (u16*)alloc(768 * 256 * 2);
  u16* Whh_h = (u16*)alloc(768 * 256 * 2); u16* Whh_l = (u16*)alloc(768 * 256 * 2);
  u16* Wr_h  = (u16*)alloc(117 * 256 * 2); u16* Wr_l  = (u16*)alloc(117 * 256 * 2);

  auto cast = [&](u16* dst, const float* src, int rows, int sc, int dc,
                  int stride, int coff) {
    int total = rows * dc;
    cast_pad_k<<<(total + 255) / 256, 256, 0, stream>>>(dst, src, rows, sc, dc,
                                                        stride, coff);
  };
  auto split = [&](u16* dh, u16* dl, const float* src, int rows, int sc, int dc,
                   int stride, int coff) {
    int total = rows * dc;
    cast_split_k<<<(total + 255) / 256, 256, 0, stream>>>(dh, dl, src, rows, sc,
                                                          dc, stride, coff);
  };
  cast(Wcomb, W_er, 256, 200, 224, 200, 0);               // rows 0..255
  wc_k<<<256, 256, 0, stream>>>(Wcf, cmb, W_m, W_er, b_er, b_m);
  cast(Wcomb + 256 * 224, Wcf, 256, 224, 224, 224, 0);    // rows 256..511
  cast(Wl1b, Wl1, 512, 256, 256, 256, 0);
  cast(Wl2b, Wl2, 512, 512, 512, 512, 0);
  split(Wnr_h, Wnr_l, W_nr, 256, 100, 128, 100, 0);
  split(Wmh_h, Wmh_l, W_m, 256, 256, 256, 512, 0);
  split(Wih_h, Wih_l, W_ih, 768, 256, 256, 256, 0);
  split(Whh_h, Whh_l, W_hh, 768, 256, 256, 256, 0);
  split(Wr_h,  Wr_l,  W_r, 117, 256, 256, 256, 0);

  const dim3 blk(256);
  // es (layer-0 e_state) + Em in one pass, edge read once
  fused_front_k<<<2048, blk, 0, stream>>>(edge, Wcomb, b_er, cmb, es, Em);
  // h0 = node @ W_nr^T + b_nr
  gemm_sp_k<false><<<dim3(8, 2), blk, 0, stream>>>(
      node, Wnr_h, Wnr_l, b_nr, hbuf, 256, 128, 100, 100, 256);

  for (int p = 0; p < 3; ++p) {
    // Hm = h @ W_mh^T
    gemm_sp_k<false><<<dim3(8, 2), blk, 0, stream>>>(
        hbuf, Wmh_h, Wmh_l, nullptr, Hm, 256, 256, 256, 256, 256);
    // fused link MLP -> adj (128 rows/block)
    link_k<<<1024, dim3(512), 0, stream>>>(es, Wl1b, bl1, Wl2b, bl2, Wl3, bl3, out_adj);
    // messages, transpose-scatter into e_state, aggregate msum
    message_k<<<dim3(128, 8), blk, 0, stream>>>(Em, Hm, out_adj, es, msum);
    // GRU gates
    gemm_sp_k<false><<<dim3(8, 6), blk, 0, stream>>>(
        msum, Wih_h, Wih_l, b_ih, gi, 768, 256, 256, 256, 768);
    gemm_sp_k<false><<<dim3(8, 6), blk, 0, stream>>>(
        hbuf, Whh_h, Whh_l, b_hh, gh, 768, 256, 256, 256, 768);
    gru_k<<<1024, 256, 0, stream>>>(gi, gh, hbuf);
  }
  // labels = h @ W_r^T + b_r
  gemm_sp_k<false><<<dim3(8, 1), blk, 0, stream>>>(
      hbuf, Wr_h, Wr_l, b_r, out_lab, 117, 256, 256, 256, 117);
}

// Round 7
// 1062.366 us; speedup vs baseline: 1.3579x; 1.1298x over previous
//
#include <hip/hip_runtime.h>
#include <math.h>

typedef unsigned short u16;
typedef __attribute__((ext_vector_type(8))) short short8;
typedef __attribute__((ext_vector_type(4))) short short4v;
typedef __attribute__((ext_vector_type(4))) float floatx4;

__device__ __forceinline__ float bf2f(u16 u) {
  union { unsigned int i; float f; } v; v.i = ((unsigned int)u) << 16; return v.f;
}
__device__ __forceinline__ u16 f2bf(float f) {
  union { unsigned int i; float f; } v; v.f = f;
  unsigned int i = v.i;
  unsigned int lsb = (i >> 16) & 1u;
  i += 0x7fffu + lsb;          // round-to-nearest-even
  return (u16)(i >> 16);
}

// ---------------------------------------------------------------------------
// Fused front GEMM: reads edge[E x 200] fp32 ONCE (coalesced float4),
// produces es = bf16(edge @ W_er^T + b_er) and Em = bf16(edge @ Wc^T + cm).
// ---------------------------------------------------------------------------
__global__ __launch_bounds__(256, 2)
void fused_front_k(const float* __restrict__ edge, const u16* __restrict__ Wcomb,
                   const float* __restrict__ b_er, const float* __restrict__ cmb,
                   u16* __restrict__ es, u16* __restrict__ Em)
{
  __shared__ __align__(16) u16 As[64 * 232];
  const int tid  = threadIdx.x;
  const int lane = tid & 63;
  const int wv   = tid >> 6;
  const int q    = lane >> 4;
  const int cl   = lane & 15;
  const long r0  = (long)blockIdx.x * 64;

  for (int z = tid; z < 64 * 24; z += 256) {
    const int zr = z / 24;
    As[zr * 232 + 200 + (z - zr * 24)] = 0;
  }
  const float4* src = (const float4*)(edge + r0 * 200);
  for (int it = tid; it < 3200; it += 256) {
    const float4 v = src[it];
    const int row = it / 50;
    const int c4  = it - row * 50;
    u16 t[4] = { f2bf(v.x), f2bf(v.y), f2bf(v.z), f2bf(v.w) };
    *(short4v*)&As[row * 232 + c4 * 4] = *(short4v*)t;
  }
  __syncthreads();

  floatx4 acc[4][8];
#pragma unroll
  for (int mi = 0; mi < 4; ++mi)
#pragma unroll
    for (int ni = 0; ni < 8; ++ni)
      acc[mi][ni] = (floatx4){0.f, 0.f, 0.f, 0.f};

  short8 b0[8], b1[8];
#pragma unroll
  for (int ni = 0; ni < 8; ++ni)
    b0[ni] = *(const short8*)(Wcomb + (long)(wv * 128 + ni * 16 + cl) * 224 + q * 8);
#pragma unroll
  for (int ks = 0; ks < 7; ++ks) {
    short8* bc = (ks & 1) ? b1 : b0;
    short8* bn = (ks & 1) ? b0 : b1;
    if (ks < 6) {
      const int kb = (ks + 1) * 32;
#pragma unroll
      for (int ni = 0; ni < 8; ++ni)
        bn[ni] = *(const short8*)(Wcomb + (long)(wv * 128 + ni * 16 + cl) * 224 + kb + q * 8);
    }
    short8 a[4];
#pragma unroll
    for (int mi = 0; mi < 4; ++mi)
      a[mi] = *(const short8*)&As[(mi * 16 + cl) * 232 + ks * 32 + q * 8];
#pragma unroll
    for (int mi = 0; mi < 4; ++mi)
#pragma unroll
      for (int ni = 0; ni < 8; ++ni)
        acc[mi][ni] = __builtin_amdgcn_mfma_f32_16x16x32_bf16(a[mi], bc[ni], acc[mi][ni], 0, 0, 0);
  }

  const bool is_ef   = (wv < 2);
  const float* bias  = is_ef ? b_er : cmb;
  u16* dst           = is_ef ? es : Em;
  const int colbase  = (wv & 1) * 128;
#pragma unroll
  for (int mi = 0; mi < 4; ++mi)
#pragma unroll
    for (int ni = 0; ni < 8; ++ni) {
      const int col = colbase + ni * 16 + cl;
      const float bb = bias[col];
#pragma unroll
      for (int r = 0; r < 4; ++r) {
        const int row = mi * 16 + q * 4 + r;
        dst[(r0 + row) * 256 + col] = f2bf(acc[mi][ni][r] + bb);
      }
    }
}

// ---------------------------------------------------------------------------
// Fused link MLP, 128 rows/block, es tile staged to LDS.
// R6 post-mortem: phase-1 re-read the es tile 8x from remote L2/L3 (512 MB
// per dispatch, unprefetched ~500-cyc hits) — the dominant stall. Now the
// 64 KB tile is staged ONCE into LDS (aliased with the low half of x1, which
// is only written after phase-1 compute finishes + barrier).
// XOR swizzle uses &15 (16 distinct chunks per quad-row group -> pure 2-way).
// ---------------------------------------------------------------------------
__global__ __launch_bounds__(512, 2)
void link_k(const u16* __restrict__ es, const u16* __restrict__ Wl1b,
            const float* __restrict__ bl1, const u16* __restrict__ Wl2b,
            const float* __restrict__ bl2, const float* __restrict__ wl3,
            const float* __restrict__ bl3, float* __restrict__ adj)
{
  __shared__ __align__(16) u16 x1b[128 * 512];   // 128 KB; [0,64K) doubles as es tile
  const int tid  = threadIdx.x;
  const int lane = tid & 63;
  const int wv   = tid >> 6;        // wave 0..7 -> 64-col slice
  const int q    = lane >> 4;
  const int cl   = lane & 15;
  const int nw0  = wv * 64;
  const long r0  = (long)blockIdx.x * 128;

  // ---- stage es tile [128 x 256 bf16] = 64 KB into LDS, swizzled ----
  {
    const short8* gsrc = (const short8*)(es + r0 * 256);   // 4096 16B-chunks
#pragma unroll
    for (int i = 0; i < 8; ++i) {
      const int g   = tid + i * 512;
      const int row = g >> 5;          // 32 chunks per row
      const int c   = g & 31;
      const short8 v = gsrc[g];
      *(short8*)&x1b[row * 256 + ((c ^ (row & 15)) << 3)] = v;
    }
  }

  floatx4 acc[8][4];
#pragma unroll
  for (int mi = 0; mi < 8; ++mi)
#pragma unroll
    for (int ni = 0; ni < 4; ++ni)
      acc[mi][ni] = (floatx4){0.f, 0.f, 0.f, 0.f};

  // first weight fragments can load while staging completes
  short8 b0[4], b1[4];
#pragma unroll
  for (int ni = 0; ni < 4; ++ni)
    b0[ni] = *(const short8*)(Wl1b + (nw0 + ni * 16 + cl) * 256 + q * 8);
  __syncthreads();

  // ---------------- phase 1: x1 = relu(es @ Wl1^T + bl1) ----------------
  {
#pragma unroll
    for (int ks = 0; ks < 8; ++ks) {
      short8* bc = (ks & 1) ? b1 : b0;
      short8* bn = (ks & 1) ? b0 : b1;
      if (ks < 7) {
        const int kb = (ks + 1) * 32;
#pragma unroll
        for (int ni = 0; ni < 4; ++ni)
          bn[ni] = *(const short8*)(Wl1b + (nw0 + ni * 16 + cl) * 256 + kb + q * 8);
      }
      short8 a[8];
#pragma unroll
      for (int mi = 0; mi < 8; ++mi) {
        const int row = mi * 16 + cl;
        a[mi] = *(const short8*)&x1b[row * 256 + (((ks * 4 + q) ^ cl) << 3)];
      }
#pragma unroll
      for (int mi = 0; mi < 8; ++mi)
#pragma unroll
        for (int ni = 0; ni < 4; ++ni)
          acc[mi][ni] = __builtin_amdgcn_mfma_f32_16x16x32_bf16(a[mi], bc[ni], acc[mi][ni], 0, 0, 0);
    }
  }
  __syncthreads();   // all waves done READING the es tile before x1 overwrites it

  // epilogue 1: write x1 (bf16) into XOR-swizzled LDS (stride 512, mask &15)
#pragma unroll
  for (int mi = 0; mi < 8; ++mi)
#pragma unroll
    for (int ni = 0; ni < 4; ++ni) {
      const int col = nw0 + ni * 16 + cl;
      const float bb = bl1[col];
      const int chunk = col >> 3;
#pragma unroll
      for (int r = 0; r < 4; ++r) {
        const int row = mi * 16 + q * 4 + r;
        const float v = fmaxf(acc[mi][ni][r] + bb, 0.f);
        x1b[row * 512 + (((chunk ^ (row & 15)) << 3) | (col & 7))] = f2bf(v);
      }
    }
#pragma unroll
  for (int mi = 0; mi < 8; ++mi)
#pragma unroll
    for (int ni = 0; ni < 4; ++ni)
      acc[mi][ni] = (floatx4){0.f, 0.f, 0.f, 0.f};
  __syncthreads();

  // ---------------- phase 2: acc = x1 @ Wl2^T ----------------
  {
    short8 c0[4], c1[4];
#pragma unroll
    for (int ni = 0; ni < 4; ++ni)
      c0[ni] = *(const short8*)(Wl2b + (nw0 + ni * 16 + cl) * 512 + q * 8);
#pragma unroll
    for (int ks = 0; ks < 16; ++ks) {
      short8* bc = (ks & 1) ? c1 : c0;
      short8* bn = (ks & 1) ? c0 : c1;
      if (ks < 15) {
        const int kb = (ks + 1) * 32;
#pragma unroll
        for (int ni = 0; ni < 4; ++ni)
          bn[ni] = *(const short8*)(Wl2b + (nw0 + ni * 16 + cl) * 512 + kb + q * 8);
      }
      short8 a[8];
#pragma unroll
      for (int mi = 0; mi < 8; ++mi) {
        const int row = mi * 16 + cl;
        a[mi] = *(const short8*)&x1b[row * 512 + (((ks * 4 + q) ^ cl) << 3)];
      }
#pragma unroll
      for (int mi = 0; mi < 8; ++mi)
#pragma unroll
        for (int ni = 0; ni < 4; ++ni)
          acc[mi][ni] = __builtin_amdgcn_mfma_f32_16x16x32_bf16(a[mi], bc[ni], acc[mi][ni], 0, 0, 0);
    }
  }

  // epilogue 2: relu(+bl2), dot wl3, reduce to adj
  float pv[8][4];
#pragma unroll
  for (int mi = 0; mi < 8; ++mi)
#pragma unroll
    for (int r = 0; r < 4; ++r) pv[mi][r] = 0.f;
#pragma unroll
  for (int mi = 0; mi < 8; ++mi)
#pragma unroll
    for (int ni = 0; ni < 4; ++ni) {
      const int col = nw0 + ni * 16 + cl;
      const float bb = bl2[col];
      const float w3 = wl3[col];
#pragma unroll
      for (int r = 0; r < 4; ++r) {
        const float v = fmaxf(acc[mi][ni][r] + bb, 0.f);
        pv[mi][r] += v * w3;
      }
    }
  __syncthreads();                    // all x1b reads done; reuse as reduce buf
  float* pf = (float*)x1b;            // [8 waves][128 rows]
#pragma unroll
  for (int mi = 0; mi < 8; ++mi)
#pragma unroll
    for (int r = 0; r < 4; ++r) {
      float p = pv[mi][r];
#pragma unroll
      for (int off = 1; off < 16; off <<= 1)
        p += __shfl_xor(p, off, 64);
      if (cl == 0) pf[wv * 128 + mi * 16 + q * 4 + r] = p;
    }
  __syncthreads();
  if (tid < 128) {
    float s = bl3[0];
#pragma unroll
    for (int w = 0; w < 8; ++w) s += pf[w * 128 + tid];
    adj[r0 + tid] = s;
  }
}

// ---------------------------------------------------------------------------
// Split-precision MFMA GEMM (~fp32 accuracy) for the h path.
// ---------------------------------------------------------------------------
template<bool OUT_BF16>
__global__ __launch_bounds__(256, 2)
void gemm_sp_k(const float* __restrict__ A, const u16* __restrict__ Bh,
               const u16* __restrict__ Bl, const float* __restrict__ bias,
               void* __restrict__ Cp,
               int N, int K_loop, int K_src, int lda, int ldc)
{
  __shared__ __align__(16) u16 Ash[128 * 40];
  __shared__ __align__(16) u16 Asl[128 * 40];
  __shared__ __align__(16) u16 Bsh[128 * 40];
  __shared__ __align__(16) u16 Bsl[128 * 40];
  const int tid  = threadIdx.x;
  const int m0   = blockIdx.x * 128;
  const int n0   = blockIdx.y * 128;
  const int lane = tid & 63;
  const int wv   = tid >> 6;
  const int wm   = wv & 1;
  const int wn   = wv >> 1;
  const int q    = lane >> 4;
  const int cl   = lane & 15;

  floatx4 acc[4][4];
#pragma unroll
  for (int i = 0; i < 4; ++i)
#pragma unroll
    for (int j = 0; j < 4; ++j)
      acc[i][j] = (floatx4){0.f, 0.f, 0.f, 0.f};

  const int srow = tid >> 1;
  const int scol = (tid & 1) * 16;

  for (int kb = 0; kb < K_loop; kb += 32) {
    {
      const long r = (long)(m0 + srow);
      u16* dh = &Ash[srow * 40 + scol];
      u16* dl = &Asl[srow * 40 + scol];
#pragma unroll
      for (int j = 0; j < 16; ++j) {
        int kg = kb + scol + j;
        float v = (kg < K_src) ? A[r * lda + kg] : 0.f;
        u16 hi = f2bf(v);
        dh[j] = hi;
        dl[j] = f2bf(v - bf2f(hi));
      }
    }
    {
      const int n = n0 + srow;
      u16* dh = &Bsh[srow * 40 + scol];
      u16* dl = &Bsl[srow * 40 + scol];
      if (n < N) {
        const short8* sh = (const short8*)(Bh + (long)n * K_loop + kb + scol);
        const short8* sl = (const short8*)(Bl + (long)n * K_loop + kb + scol);
        ((short8*)dh)[0] = sh[0]; ((short8*)dh)[1] = sh[1];
        ((short8*)dl)[0] = sl[0]; ((short8*)dl)[1] = sl[1];
      } else {
#pragma unroll
        for (int j = 0; j < 16; ++j) { dh[j] = 0; dl[j] = 0; }
      }
    }
    __syncthreads();

    short8 ah[4], al[4], bh[4], bl[4];
#pragma unroll
    for (int mi = 0; mi < 4; ++mi) {
      ah[mi] = *(const short8*)&Ash[(wm * 64 + mi * 16 + cl) * 40 + q * 8];
      al[mi] = *(const short8*)&Asl[(wm * 64 + mi * 16 + cl) * 40 + q * 8];
    }
#pragma unroll
    for (int ni = 0; ni < 4; ++ni) {
      bh[ni] = *(const short8*)&Bsh[(wn * 64 + ni * 16 + cl) * 40 + q * 8];
      bl[ni] = *(const short8*)&Bsl[(wn * 64 + ni * 16 + cl) * 40 + q * 8];
    }
#pragma unroll
    for (int mi = 0; mi < 4; ++mi)
#pragma unroll
      for (int ni = 0; ni < 4; ++ni) {
        acc[mi][ni] = __builtin_amdgcn_mfma_f32_16x16x32_bf16(ah[mi], bh[ni], acc[mi][ni], 0, 0, 0);
        acc[mi][ni] = __builtin_amdgcn_mfma_f32_16x16x32_bf16(al[mi], bh[ni], acc[mi][ni], 0, 0, 0);
        acc[mi][ni] = __builtin_amdgcn_mfma_f32_16x16x32_bf16(ah[mi], bl[ni], acc[mi][ni], 0, 0, 0);
      }
    __syncthreads();
  }

#pragma unroll
  for (int mi = 0; mi < 4; ++mi) {
    const int row = m0 + wm * 64 + mi * 16 + q * 4;
#pragma unroll
    for (int ni = 0; ni < 4; ++ni) {
      const int col = n0 + wn * 64 + ni * 16 + cl;
      if (col < N) {
        const float b = bias ? bias[col] : 0.f;
#pragma unroll
        for (int r = 0; r < 4; ++r) {
          float v = acc[mi][ni][r] + b;
          const long off = (long)(row + r) * ldc + col;
          if (OUT_BF16) ((u16*)Cp)[off] = f2bf(v);
          else          ((float*)Cp)[off] = v;
        }
      }
    }
  }
}

__global__ void cast_pad_k(u16* __restrict__ dst, const float* __restrict__ src,
                           int rows, int src_cols, int dst_cols, int src_stride,
                           int col_off)
{
  int idx = blockIdx.x * blockDim.x + threadIdx.x;
  int total = rows * dst_cols;
  if (idx >= total) return;
  int r = idx / dst_cols, c = idx - r * dst_cols;
  float v = (c < src_cols) ? src[r * src_stride + col_off + c] : 0.f;
  dst[idx] = f2bf(v);
}

__global__ void cast_split_k(u16* __restrict__ dh, u16* __restrict__ dl,
                             const float* __restrict__ src,
                             int rows, int src_cols, int dst_cols, int src_stride,
                             int col_off)
{
  int idx = blockIdx.x * blockDim.x + threadIdx.x;
  int total = rows * dst_cols;
  if (idx >= total) return;
  int r = idx / dst_cols, c = idx - r * dst_cols;
  float v = (c < src_cols) ? src[r * src_stride + col_off + c] : 0.f;
  u16 hi = f2bf(v);
  dh[idx] = hi;
  dl[idx] = f2bf(v - bf2f(hi));
}

// Wcf = W_me @ W_er (fp32, [256 x 224] zero-padded); c_m = W_me @ b_er + b_m
__global__ void wc_k(float* __restrict__ Wcf, float* __restrict__ cm,
                     const float* __restrict__ W_m, const float* __restrict__ W_er,
                     const float* __restrict__ b_er, const float* __restrict__ b_m)
{
  int o = blockIdx.x;
  int t = threadIdx.x;
  __shared__ float wme[256];
  wme[t] = W_m[o * 512 + 256 + t];
  __syncthreads();
  if (t < 224) {
    float s = 0.f;
    if (t < 200) {
      for (int c = 0; c < 256; ++c) s += wme[c] * W_er[c * 200 + t];
    }
    Wcf[o * 224 + t] = s;
  }
  if (t == 0) {
    float s = 0.f;
    for (int c = 0; c < 256; ++c) s += wme[c] * b_er[c];
    cm[o] = s + b_m[o];
  }
}

// Per-edge message + transpose-scatter + per-target aggregation.
__global__ __launch_bounds__(256)
void message_k(const u16* __restrict__ Em, const float* __restrict__ Hm,
               const float* __restrict__ adj, u16* __restrict__ es,
               float* __restrict__ msum)
{
  const int b = blockIdx.y, i = blockIdx.x;
  const int tid = threadIdx.x;
  const int c = tid & 31;
  const int g = tid >> 5;
  __shared__ float red[8][256];
  float accv[8] = {0.f, 0.f, 0.f, 0.f, 0.f, 0.f, 0.f, 0.f};
  const long base_bi = ((long)(b * 128 + i)) * 128;
  for (int w0 = 0; w0 < 128; w0 += 8) {
    const int w = w0 + g;
    const float a = adj[base_bi + w];
    const float s = 1.f / (1.f + __expf(-a));
    const short8 ev = *(const short8*)(Em + (base_bi + w) * 256 + c * 8);
    const float* hp = Hm + ((long)(b * 128 + w)) * 256 + c * 8;
    u16 mb[8];
#pragma unroll
    for (int j = 0; j < 8; ++j) {
      float x = bf2f(((const u16*)&ev)[j]) + hp[j];
      x = fmaxf(x, 0.f) * s;
      accv[j] += x;
      mb[j] = f2bf(x);
    }
    *(short8*)(es + (((long)(b * 128 + w)) * 128 + i) * 256 + c * 8) = *(short8*)mb;
  }
#pragma unroll
  for (int j = 0; j < 8; ++j) red[g][c * 8 + j] = accv[j];
  __syncthreads();
  float s = 0.f;
#pragma unroll
  for (int gg = 0; gg < 8; ++gg) s += red[gg][tid];
  msum[((long)(b * 128 + i)) * 256 + tid] = s;
}

__global__ void gru_k(const float* __restrict__ gi, const float* __restrict__ gh,
                      float* __restrict__ h)
{
  const int n = blockIdx.x;
  const int d = threadIdx.x;
  const int base = n * 768;
  const float r  = 1.f / (1.f + __expf(-(gi[base + d] + gh[base + d])));
  const float z  = 1.f / (1.f + __expf(-(gi[base + 256 + d] + gh[base + 256 + d])));
  const float nn = tanhf(gi[base + 512 + d] + r * gh[base + 512 + d]);
  const int hi = n * 256 + d;
  h[hi] = (1.f - z) * nn + z * h[hi];
}

extern "C" void kernel_launch(void* const* d_in, const int* in_sizes, int n_in,
                              void* d_out, int out_size, void* d_ws, size_t ws_size,
                              hipStream_t stream)
{
  const float* edge = (const float*)d_in[0];
  const float* node = (const float*)d_in[1];
  const float* W_er = (const float*)d_in[2];
  const float* b_er = (const float*)d_in[3];
  const float* W_nr = (const float*)d_in[4];
  const float* b_nr = (const float*)d_in[5];
  const float* Wl1  = (const float*)d_in[6];
  const float* bl1  = (const float*)d_in[7];
  const float* Wl2  = (const float*)d_in[8];
  const float* bl2  = (const float*)d_in[9];
  const float* Wl3  = (const float*)d_in[10];
  const float* bl3  = (const float*)d_in[11];
  const float* W_m  = (const float*)d_in[12];
  const float* b_m  = (const float*)d_in[13];
  const float* W_ih = (const float*)d_in[14];
  const float* b_ih = (const float*)d_in[15];
  const float* W_hh = (const float*)d_in[16];
  const float* b_hh = (const float*)d_in[17];
  const float* W_r  = (const float*)d_in[18];
  const float* b_r  = (const float*)d_in[19];
  (void)in_sizes; (void)n_in; (void)out_size; (void)ws_size;

  float* out_adj = (float*)d_out;            // [8,128,128]
  float* out_lab = (float*)d_out + 131072;   // [8,128,117]

  char* ws = (char*)d_ws;
  size_t off = 0;
  auto alloc = [&](size_t bytes) -> void* {
    void* p = ws + off; off += (bytes + 255) & ~(size_t)255; return p;
  };
  const long E = 131072;
  u16*   es   = (u16*)  alloc(E * 256 * 2);
  u16*   Em   = (u16*)  alloc(E * 256 * 2);
  float* Hm   = (float*)alloc(1024 * 256 * 4);
  float* hbuf = (float*)alloc(1024 * 256 * 4);
  float* msum = (float*)alloc(1024 * 256 * 4);
  float* gi   = (float*)alloc(1024 * 768 * 4);
  float* gh   = (float*)alloc(1024 * 768 * 4);
  u16*   Wcomb = (u16*) alloc(512 * 224 * 2); // [W_er ; W_me@W_er] bf16
  u16*   Wl1b = (u16*)  alloc(512 * 256 * 2);
  u16*   Wl2b = (u16*)  alloc(512 * 512 * 2);
  float* Wcf  = (float*)alloc(256 * 224 * 4);
  float* cmb  = (float*)alloc(256 * 4);
  u16* Wnr_h = (u16*)alloc(256 * 128 * 2); u16* Wnr_l = (u16*)alloc(256 * 128 * 2);
  u16* Wmh_h = (u16*)alloc(256 * 256 * 2); u16* Wmh_l = (u16*)alloc(256 * 256 * 2);
  u16* Wih_h = (u16*)alloc(768 * 256 * 2); u16* Wih_l = (u16*)alloc(768 * 256 * 2);
  u16* Whh_h = (u16*)alloc(768 * 256 * 2); u16* Whh_l = (u16*)alloc(768 * 256 * 2);
  u16* Wr_h  = (u16*)alloc(117 * 256 * 2); u16* Wr_l  = (u16*)alloc(117 * 256 * 2);

  auto cast = [&](u16* dst, const float* src, int rows, int sc, int dc,
                  int stride, int coff) {
    int total = rows * dc;
    cast_pad_k<<<(total + 255) / 256, 256, 0, stream>>>(dst, src, rows, sc, dc,
                                                        stride, coff);
  };
  auto split = [&](u16* dh, u16* dl, const float* src, int rows, int sc, int dc,
                   int stride, int coff) {
    int total = rows * dc;
    cast_split_k<<<(total + 255) / 256, 256, 0, stream>>>(dh, dl, src, rows, sc,
                                                          dc, stride, coff);
  };
  cast(Wcomb, W_er, 256, 200, 224, 200, 0);               // rows 0..255
  wc_k<<<256, 256, 0, stream>>>(Wcf, cmb, W_m, W_er, b_er, b_m);
  cast(Wcomb + 256 * 224, Wcf, 256, 224, 224, 224, 0);    // rows 256..511
  cast(Wl1b, Wl1, 512, 256, 256, 256, 0);
  cast(Wl2b, Wl2, 512, 512, 512, 512, 0);
  split(Wnr_h, Wnr_l, W_nr, 256, 100, 128, 100, 0);
  split(Wmh_h, Wmh_l, W_m, 256, 256, 256, 512, 0);
  split(Wih_h, Wih_l, W_ih, 768, 256, 256, 256, 0);
  split(Whh_h, Whh_l, W_hh, 768, 256, 256, 256, 0);
  split(Wr_h,  Wr_l,  W_r, 117, 256, 256, 256, 0);

  const dim3 blk(256);
  // es (layer-0 e_state) + Em in one pass, edge read once
  fused_front_k<<<2048, blk, 0, stream>>>(edge, Wcomb, b_er, cmb, es, Em);
  // h0 = node @ W_nr^T + b_nr
  gemm_sp_k<false><<<dim3(8, 2), blk, 0, stream>>>(
      node, Wnr_h, Wnr_l, b_nr, hbuf, 256, 128, 100, 100, 256);

  for (int p = 0; p < 3; ++p) {
    // Hm = h @ W_mh^T
    gemm_sp_k<false><<<dim3(8, 2), blk, 0, stream>>>(
        hbuf, Wmh_h, Wmh_l, nullptr, Hm, 256, 256, 256, 256, 256);
    // fused link MLP -> adj (128 rows/block, es tile staged to LDS)
    link_k<<<1024, dim3(512), 0, stream>>>(es, Wl1b, bl1, Wl2b, bl2, Wl3, bl3, out_adj);
    // messages, transpose-scatter into e_state, aggregate msum
    message_k<<<dim3(128, 8), blk, 0, stream>>>(Em, Hm, out_adj, es, msum);
    // GRU gates
    gemm_sp_k<false><<<dim3(8, 6), blk, 0, stream>>>(
        msum, Wih_h, Wih_l, b_ih, gi, 768, 256, 256, 256, 768);
    gemm_sp_k<false><<<dim3(8, 6), blk, 0, stream>>>(
        hbuf, Whh_h, Whh_l, b_hh, gh, 768, 256, 256, 256, 768);
    gru_k<<<1024, 256, 0, stream>>>(gi, gh, hbuf);
  }
  // labels = h @ W_r^T + b_r
  gemm_sp_k<false><<<dim3(8, 1), blk, 0, stream>>>(
      hbuf, Wr_h, Wr_l, b_r, out_lab, 117, 256, 256, 256, 117);
}